// Round 6
// baseline (217.240 us; speedup 1.0000x reference)
//
#include <hip/hip_runtime.h>

// SSIM loss, fp32, x/y: (32,3,512,512), scalar mean output.
// R8: single-wave blocks + RPW=16 (dual-lever discriminator).
//   R7 post-mortem: pinned 3-row pipeline (VGPR 64, loads verifiably in
//   flight) bought only 3 us -> latency/TLP hypotheses dead. All rounds
//   converge on ~3.0 TB/s below-L2 service of ~250 MB traffic.
//   Two live hypotheses:
//     H-traffic:  bound by ~3 TB/s L3/fabric -> cut halo over-fetch
//                 (10/8 = 1.25x  ->  18/16 = 1.125x with RPW=16).
//     H-geometry: resident waves stuck ~10/CU by 4-wave-block granularity
//                 -> 64-thread (1-wave) blocks, no barriers, no LDS.
//   This round moves both levers: 6144 single-wave blocks (24 waves/CU
//   demand), RPW=16, pipeline/numerics byte-identical to R7.
//   Tripwires: VGPR ~64-80, WRITE_SIZE ~0.1 MB (else spill -> revert).

#define IMG_H 512
#define IMG_W 512
#define N_PLANES 96                    // 32 * 3
#define TILE_W 256
#define N_TILES 2
#define RPW 16                         // rows per wave
#define STRIPS (IMG_H / RPW)           // 32
#define N_MAIN_BLOCKS (N_PLANES * N_TILES * STRIPS)   // 6144 single-wave blocks
#define TOTAL_ELEMS 25165824.0f        // 32*3*512*512

typedef float f4 __attribute__((ext_vector_type(4)));

__device__ __forceinline__ int reflect512(int i) {
    i = i < 0 ? -i : i;
    return i > (IMG_H - 1) ? (2 * (IMG_H - 1) - i) : i;
}

// Overlapping 16B loads: A covers cols [4L-1..4L+2], B covers [4L+1..4L+4].
struct RowRaw { f4 xA, xB, yA, yB; };

struct H {           // horizontal 3-tap sums for this lane's 4 output columns
    float x[4], y[4], xx[4], yy[4], xy[4];
};

// 3-tap sums of 4 consecutive windows over 6 elements, sharing pair sums.
__device__ __forceinline__ void tri3(const float e[6], float o[4]) {
    const float p12 = e[1] + e[2];
    const float p34 = e[3] + e[4];
    o[0] = e[0] + p12;
    o[1] = p12 + e[3];
    o[2] = e[2] + p34;
    o[3] = p34 + e[5];
}

__device__ __forceinline__ H build_h(const RowRaw& rw, bool Ledge, bool Redge) {
    // Normal lanes: e = {A.x,A.y,A.z,A.w,B.z,B.w} = cols 4L-1..4L+4.
    float x6[6] = { rw.xA.x, rw.xA.y, rw.xA.z, rw.xA.w, rw.xB.z, rw.xB.w };
    float y6[6] = { rw.yA.x, rw.yA.y, rw.yA.z, rw.yA.w, rw.yB.z, rw.yB.w };
    if (Ledge) {
        // A clamped to col 0: {c0,c1,c2,c3}; desired {reflect(-1)=c1,c0,c1,c2}.
        x6[0] = rw.xA.y; x6[1] = rw.xA.x; x6[2] = rw.xA.y; x6[3] = rw.xA.z;
        y6[0] = rw.yA.y; y6[1] = rw.yA.x; y6[2] = rw.yA.y; y6[3] = rw.yA.z;
    }
    if (Redge) {
        // B clamped to col 508: {c508..c511}; desired e4=c511=B.w,
        // e5=reflect(512)=c510=B.z.
        x6[4] = rw.xB.w; x6[5] = rw.xB.z;
        y6[4] = rw.yB.w; y6[5] = rw.yB.z;
    }

    float xx6[6], yy6[6], xy6[6];
    #pragma unroll
    for (int i = 0; i < 6; ++i) {
        xx6[i] = x6[i] * x6[i];
        yy6[i] = y6[i] * y6[i];
        xy6[i] = x6[i] * y6[i];
    }
    H h;
    tri3(x6,  h.x);
    tri3(y6,  h.y);
    tri3(xx6, h.xx);
    tri3(yy6, h.yy);
    tri3(xy6, h.xy);
    return h;
}

__device__ __forceinline__ void ssim_step(const H& h0, const H& h1, const H& h2,
                                          float& acc) {
    const float C1v  = 0.0001f;   // 0.01^2
    const float C2v  = 0.0009f;   // 0.03^2
    const float inv9 = 1.0f / 9.0f;
    #pragma unroll
    for (int j = 0; j < 4; ++j) {
        const float sx  = h0.x[j]  + h1.x[j]  + h2.x[j];
        const float sy  = h0.y[j]  + h1.y[j]  + h2.y[j];
        const float sxx = h0.xx[j] + h1.xx[j] + h2.xx[j];
        const float syy = h0.yy[j] + h1.yy[j] + h2.yy[j];
        const float sxy = h0.xy[j] + h1.xy[j] + h2.xy[j];

        const float mux   = sx * inv9;
        const float muy   = sy * inv9;
        const float mux2  = mux * mux;
        const float muy2  = muy * muy;
        const float muxy  = mux * muy;
        const float sigx  = fmaf(sxx, inv9, -mux2);
        const float sigy  = fmaf(syy, inv9, -muy2);
        const float sigxy = fmaf(sxy, inv9, -muxy);

        const float nume = (2.0f * muxy + C1v) * (2.0f * sigxy + C2v);
        const float deno = (mux2 + muy2 + C1v) * (sigx + sigy + C2v);
        float v = fmaf(nume, -__builtin_amdgcn_rcpf(deno), 1.0f) * 0.5f;
        v = fminf(fmaxf(v, 0.0f), 1.0f);
        acc += v;
    }
}

// Issue one row's 4 loads via un-sinkable volatile asm. One instruction per
// asm block; "=&v" early-clobber so outputs can never alias the address
// operand; address is a plain C++ pointer -> 64-bit VGPR pair.
#define ISSUE_ROW(BUF, ROW) do {                                          \
    const size_t ro_ = (size_t)reflect512(ROW) * IMG_W;                   \
    const float* pxA_ = pxA0 + ro_;                                       \
    const float* pxB_ = pxB0 + ro_;                                       \
    const float* pyA_ = pyA0 + ro_;                                       \
    const float* pyB_ = pyB0 + ro_;                                       \
    asm volatile("global_load_dwordx4 %0, %1, off"                        \
                 : "=&v"((BUF).xA) : "v"(pxA_));                          \
    asm volatile("global_load_dwordx4 %0, %1, off"                        \
                 : "=&v"((BUF).xB) : "v"(pxB_));                          \
    asm volatile("global_load_dwordx4 %0, %1, off"                        \
                 : "=&v"((BUF).yA) : "v"(pyA_));                          \
    asm volatile("global_load_dwordx4 %0, %1, off"                        \
                 : "=&v"((BUF).yB) : "v"(pyB_));                          \
} while (0)

// Counted wait for BUF's 4 loads (oldest outstanding). "+v" ties make all
// consumers data-depend on the post-wait values; sched_barrier per rule 18.
#define WAIT_ROW(BUF, NSTR) do {                                          \
    asm volatile("s_waitcnt vmcnt(" NSTR ")"                              \
                 : "+v"((BUF).xA), "+v"((BUF).xB),                        \
                   "+v"((BUF).yA), "+v"((BUF).yB));                       \
    __builtin_amdgcn_sched_barrier(0);                                    \
} while (0)

#define STEP(BUF) do {                                                    \
    H h2 = build_h((BUF), Ledge, Redge);                                  \
    ssim_step(h0, h1, h2, acc);                                           \
    h0 = h1; h1 = h2;                                                     \
} while (0)

// Steady-state cycle: issue next row into BI, wait+consume BW (2 rows stay
// in flight -> vmcnt(8), never 0 mid-loop).
#define CYCLE(BI, ROW, BW) do {                                           \
    ISSUE_ROW(BI, ROW); WAIT_ROW(BW, "8"); STEP(BW);                      \
} while (0)

__global__ __launch_bounds__(64, 4)
void ssim_main_kernel(const float* __restrict__ x, const float* __restrict__ y,
                      float* __restrict__ partials) {
    const int blk   = blockIdx.x;
    const int plane = blk / (N_TILES * STRIPS);
    const int rem   = blk % (N_TILES * STRIPS);
    const int tile  = rem / STRIPS;
    const int strip = rem % STRIPS;
    const int lane  = threadIdx.x;                     // 0..63, single wave

    const int c0   = tile * TILE_W;
    const int vidx = (c0 >> 2) + lane;                 // global float4 idx 0..127
    const bool Ledge = (vidx == 0);
    const bool Redge = (vidx == 127);
    const int offA = Ledge ? 0   : (4 * vidx - 1);     // float offsets, 4B-aligned
    const int offB = Redge ? 508 : (4 * vidx + 1);
    const int r0   = strip * RPW;

    const float* px = x + (size_t)plane * (IMG_H * IMG_W);
    const float* py = y + (size_t)plane * (IMG_H * IMG_W);
    const float* pxA0 = px + offA;
    const float* pxB0 = px + offB;
    const float* pyA0 = py + offA;
    const float* pyB0 = py + offB;

    RowRaw B0, B1, B2;
    float acc = 0.0f;

    // Pipeline prologue: rows r0-1, r0, r0+1 in flight (12 loads).
    ISSUE_ROW(B0, r0 - 1);
    ISSUE_ROW(B1, r0);
    ISSUE_ROW(B2, r0 + 1);
    WAIT_ROW(B0, "8");
    H h0 = build_h(B0, Ledge, Redge);
    ISSUE_ROW(B0, r0 + 2);
    WAIT_ROW(B1, "8");
    H h1 = build_h(B1, Ledge, Redge);

    // Steady state: 14 cycles consuming rows r0+1 .. r0+14 (outputs
    // r0 .. r0+13), buffers rotate B1,B2,B0,...; then 2-drain for rows
    // r0+15, r0+16 (outputs r0+14, r0+15). No trailing waste.
    CYCLE(B1, r0 + 3,  B2);
    CYCLE(B2, r0 + 4,  B0);
    CYCLE(B0, r0 + 5,  B1);
    CYCLE(B1, r0 + 6,  B2);
    CYCLE(B2, r0 + 7,  B0);
    CYCLE(B0, r0 + 8,  B1);
    CYCLE(B1, r0 + 9,  B2);
    CYCLE(B2, r0 + 10, B0);
    CYCLE(B0, r0 + 11, B1);
    CYCLE(B1, r0 + 12, B2);
    CYCLE(B2, r0 + 13, B0);
    CYCLE(B0, r0 + 14, B1);
    CYCLE(B1, r0 + 15, B2);
    CYCLE(B2, r0 + 16, B0);
    /* drain */ WAIT_ROW(B1, "4"); STEP(B1);
    /* drain */ WAIT_ROW(B2, "0"); STEP(B2);

    // Single-wave block: wave reduction, lane 0 writes the block partial.
    #pragma unroll
    for (int off = 32; off > 0; off >>= 1)
        acc += __shfl_down(acc, off);
    if (lane == 0) partials[blk] = acc;
}

__global__ void ssim_reduce_kernel(const float* __restrict__ partials,
                                   float* __restrict__ out) {
    float acc = 0.0f;
    for (int i = threadIdx.x; i < N_MAIN_BLOCKS; i += 256)
        acc += partials[i];
    #pragma unroll
    for (int off = 32; off > 0; off >>= 1)
        acc += __shfl_down(acc, off);
    __shared__ float wave_sums[4];
    const int wave = threadIdx.x >> 6;
    const int lane = threadIdx.x & 63;
    if (lane == 0) wave_sums[wave] = acc;
    __syncthreads();
    if (threadIdx.x == 0)
        out[0] = (wave_sums[0] + wave_sums[1] + wave_sums[2] + wave_sums[3])
                 * (1.0f / TOTAL_ELEMS);
}

extern "C" void kernel_launch(void* const* d_in, const int* in_sizes, int n_in,
                              void* d_out, int out_size, void* d_ws, size_t ws_size,
                              hipStream_t stream) {
    const float* x = (const float*)d_in[0];
    const float* y = (const float*)d_in[1];
    float* out      = (float*)d_out;
    float* partials = (float*)d_ws;   // N_MAIN_BLOCKS floats (24 KiB)

    ssim_main_kernel<<<N_MAIN_BLOCKS, 64, 0, stream>>>(x, y, partials);
    ssim_reduce_kernel<<<1, 256, 0, stream>>>(partials, out);
}